// Round 9
// baseline (1892.686 us; speedup 1.0000x reference)
//
#include <hip/hip_runtime.h>

typedef float v2f __attribute__((ext_vector_type(2)));

#define QN 8192   // trajectories
#define MN 2048   // time steps
#define HN 64     // hidden units
#define LPT 16    // lanes per group; each group carries TWO trajectories
#define UPL 4     // hidden units per lane

// DPP butterfly add (old = v: no zero-materialization; full masks).
template <int CTRL>
__device__ __forceinline__ float dpp_add(float v) {
    int m = __builtin_amdgcn_update_dpp(__float_as_int(v), __float_as_int(v),
                                        CTRL, 0xf, 0xf, true);
    return v + __int_as_float(m);
}
#define DPP_QUAD_XOR1 0xB1   // quad_perm [1,0,3,2]
#define DPP_QUAD_XOR2 0x4E   // quad_perm [2,3,0,1]
#define DPP_HALF_MIRR 0x141  // row_half_mirror
#define DPP_ROW_MIRR  0x140  // row_mirror

__device__ __forceinline__ v2f vfma(v2f a, v2f b, v2f c) {
    return __builtin_elementwise_fma(a, b, c);
}

__global__ __launch_bounds__(256, 1) void rk4_nss_kernel(
    const float* __restrict__ x0p,   // (Q,2)
    const float* __restrict__ up,    // (M,Q)
    const float* __restrict__ W1,    // (3,H)
    const float* __restrict__ b1,    // (H)
    const float* __restrict__ W2,    // (H,2)
    const float* __restrict__ b2,    // (2)
    float* __restrict__ out)         // (M,Q,2)
{
    const int tid   = blockIdx.x * 256 + threadIdx.x;
    const int glane = threadIdx.x & (LPT - 1);
    const int gid   = tid >> 4;            // 16-lane group id, 0..4095
    const int trajA = 2 * gid;             // group carries trajectories A,B

    const float SC = 2.8853900817779268f;  // 2*log2(e): e^{2x} = 2^(SC*x)
    const float CL = 27.0f;  // clamp (scaled): tanh(27/SC)==1.0f in f32;
                             // pair den-product <= ~2^54, cannot overflow.

    // Shared weights (same hidden units serve both trajectories).
    // W1,b1 pre-scaled by SC; tanh = 1 - 2/(e^{2x}+1): "+1" folded into c0,c1
    // (applied once per step), accumulate inv*(-2*W2).
    v2f W10[2], W11[2], W12[2], BS[2];
    float w20n[UPL], w21n[UPL];
#pragma unroll
    for (int k = 0; k < UPL; ++k) {
        const int j = glane + k * LPT;
        W10[k >> 1][k & 1] = W1[j] * SC;
        W11[k >> 1][k & 1] = W1[HN + j] * SC;
        W12[k >> 1][k & 1] = W1[2 * HN + j] * SC;
        BS[k >> 1][k & 1]  = b1[j] * SC;
        w20n[k] = -2.0f * W2[2 * j];
        w21n[k] = -2.0f * W2[2 * j + 1];
    }
    float c0 = b2[0], c1 = b2[1];
    for (int j = 0; j < HN; ++j) {   // init-time only; W2 is 512 B, cache-hot
        c0 += W2[2 * j];
        c1 += W2[2 * j + 1];
    }
    const float c0h = 0.5f * c0, c1h = 0.5f * c1;

    // Trajectory state, duplicated (A,B): two independent dependency chains
    // per wave to fill each other's latency stalls at 1 wave/SIMD.
    float xaA = x0p[2 * trajA],     xbA = x0p[2 * trajA + 1];
    float xaB = x0p[2 * trajA + 2], xbB = x0p[2 * trajA + 3];

    float2* op = reinterpret_cast<float2*>(out) + trajA;
    const bool writer = (glane < 2);
    const bool isA    = (glane == 0);

    v2f PBA[2], PBB[2];  // u-dependent preactivation parts

    // Dual feval: returns RAW p values (k_true = p + c, folded by caller).
    auto feval2 = [&](float iaA_, float ibA_, float iaB_, float ibB_,
                      float& p0A, float& p1A, float& p0B, float& p1B) {
        v2f IAA = {iaA_, iaA_}, IBA = {ibA_, ibA_};
        v2f IAB = {iaB_, iaB_}, IBB = {ibB_, ibB_};
        v2f PA0 = vfma(W10[0], IAA, vfma(W11[0], IBA, PBA[0]));
        v2f PA1 = vfma(W10[1], IAA, vfma(W11[1], IBA, PBA[1]));
        v2f PB0 = vfma(W10[0], IAB, vfma(W11[0], IBB, PBB[0]));
        v2f PB1 = vfma(W10[1], IAB, vfma(W11[1], IBB, PBB[1]));

        float dA0 = __builtin_amdgcn_exp2f(__builtin_amdgcn_fmed3f(PA0.x, -CL, CL)) + 1.0f;
        float dA1 = __builtin_amdgcn_exp2f(__builtin_amdgcn_fmed3f(PA0.y, -CL, CL)) + 1.0f;
        float dA2 = __builtin_amdgcn_exp2f(__builtin_amdgcn_fmed3f(PA1.x, -CL, CL)) + 1.0f;
        float dA3 = __builtin_amdgcn_exp2f(__builtin_amdgcn_fmed3f(PA1.y, -CL, CL)) + 1.0f;
        float dB0 = __builtin_amdgcn_exp2f(__builtin_amdgcn_fmed3f(PB0.x, -CL, CL)) + 1.0f;
        float dB1 = __builtin_amdgcn_exp2f(__builtin_amdgcn_fmed3f(PB0.y, -CL, CL)) + 1.0f;
        float dB2 = __builtin_amdgcn_exp2f(__builtin_amdgcn_fmed3f(PB1.x, -CL, CL)) + 1.0f;
        float dB3 = __builtin_amdgcn_exp2f(__builtin_amdgcn_fmed3f(PB1.y, -CL, CL)) + 1.0f;

        // Pair-batched reciprocal (R3-proven): 4 independent rcp chains.
        float rA01 = __builtin_amdgcn_rcpf(dA0 * dA1);
        float rA23 = __builtin_amdgcn_rcpf(dA2 * dA3);
        float rB01 = __builtin_amdgcn_rcpf(dB0 * dB1);
        float rB23 = __builtin_amdgcn_rcpf(dB2 * dB3);
        float iA0 = rA01 * dA1, iA1 = rA01 * dA0;
        float iA2 = rA23 * dA3, iA3 = rA23 * dA2;
        float iB0 = rB01 * dB1, iB1 = rB01 * dB0;
        float iB2 = rB23 * dB3, iB3 = rB23 * dB2;

        float q0A = fmaf(iA0, w20n[0], fmaf(iA1, w20n[1],
                    fmaf(iA2, w20n[2], iA3 * w20n[3])));
        float q1A = fmaf(iA0, w21n[0], fmaf(iA1, w21n[1],
                    fmaf(iA2, w21n[2], iA3 * w21n[3])));
        float q0B = fmaf(iB0, w20n[0], fmaf(iB1, w20n[1],
                    fmaf(iB2, w20n[2], iB3 * w20n[3])));
        float q1B = fmaf(iB0, w21n[0], fmaf(iB1, w21n[1],
                    fmaf(iB2, w21n[2], iB3 * w21n[3])));

        // Four independent DPP reduce chains (within 16-lane rows).
        q0A = dpp_add<DPP_QUAD_XOR1>(q0A);  q1A = dpp_add<DPP_QUAD_XOR1>(q1A);
        q0B = dpp_add<DPP_QUAD_XOR1>(q0B);  q1B = dpp_add<DPP_QUAD_XOR1>(q1B);
        q0A = dpp_add<DPP_QUAD_XOR2>(q0A);  q1A = dpp_add<DPP_QUAD_XOR2>(q1A);
        q0B = dpp_add<DPP_QUAD_XOR2>(q0B);  q1B = dpp_add<DPP_QUAD_XOR2>(q1B);
        q0A = dpp_add<DPP_HALF_MIRR>(q0A);  q1A = dpp_add<DPP_HALF_MIRR>(q1A);
        q0B = dpp_add<DPP_HALF_MIRR>(q0B);  q1B = dpp_add<DPP_HALF_MIRR>(q1B);
        q0A = dpp_add<DPP_ROW_MIRR>(q0A);   q1A = dpp_add<DPP_ROW_MIRR>(q1A);
        q0B = dpp_add<DPP_ROW_MIRR>(q0B);   q1B = dpp_add<DPP_ROW_MIRR>(q1B);
        p0A = q0A; p1A = q1A; p0B = q0B; p1B = q1B;
    };

    // One RK4 step for both trajectories, with the +c folds:
    //   x+0.5*k1 = (x+0.5c)+0.5*p1 ; x+k3 = (x+c)+p3 ; x' = (x+c)+(Σ)/6
    auto step2 = [&](float uA, float uB) {
        v2f UA = {uA, uA}, UB = {uB, uB};
        PBA[0] = vfma(W12[0], UA, BS[0]);
        PBA[1] = vfma(W12[1], UA, BS[1]);
        PBB[0] = vfma(W12[0], UB, BS[0]);
        PBB[1] = vfma(W12[1], UB, BS[1]);

        const float xhaA = xaA + c0h, xhbA = xbA + c1h;
        const float xcaA = xaA + c0,  xcbA = xbA + c1;
        const float xhaB = xaB + c0h, xhbB = xbB + c1h;
        const float xcaB = xaB + c0,  xcbB = xbB + c1;

        float p1aA, p1bA, p2aA, p2bA, p3aA, p3bA, p4aA, p4bA;
        float p1aB, p1bB, p2aB, p2bB, p3aB, p3bB, p4aB, p4bB;
        feval2(xaA, xbA, xaB, xbB, p1aA, p1bA, p1aB, p1bB);
        feval2(fmaf(0.5f, p1aA, xhaA), fmaf(0.5f, p1bA, xhbA),
               fmaf(0.5f, p1aB, xhaB), fmaf(0.5f, p1bB, xhbB),
               p2aA, p2bA, p2aB, p2bB);
        feval2(fmaf(0.5f, p2aA, xhaA), fmaf(0.5f, p2bA, xhbA),
               fmaf(0.5f, p2aB, xhaB), fmaf(0.5f, p2bB, xhbB),
               p3aA, p3bA, p3aB, p3bB);
        feval2(xcaA + p3aA, xcbA + p3bA, xcaB + p3aB, xcbB + p3bB,
               p4aA, p4bA, p4aB, p4bB);

        xaA = fmaf(1.0f / 6.0f, fmaf(2.0f, p2aA + p3aA, p1aA + p4aA), xcaA);
        xbA = fmaf(1.0f / 6.0f, fmaf(2.0f, p2bA + p3bA, p1bA + p4bA), xcbA);
        xaB = fmaf(1.0f / 6.0f, fmaf(2.0f, p2aB + p3aB, p1aB + p4aB), xcaB);
        xbB = fmaf(1.0f / 6.0f, fmaf(2.0f, p2bB + p3bB, p1bB + p4bB), xcbB);
    };

    // u for both trajectories of this group is adjacent: one float2 load.
    const float2* upv = reinterpret_cast<const float2*>(up) + gid;
    float2 u01 = upv[0];
    float2 u23 = upv[QN / 2];

    for (int t = 0; t < MN; t += 2) {
        // Prefetch 2 steps ahead (consumed next unrolled iteration).
        const float2 un0 = (t + 2 < MN) ? upv[(t + 2) * (QN / 2)]
                                        : make_float2(0.0f, 0.0f);
        const float2 un1 = (t + 3 < MN) ? upv[(t + 3) * (QN / 2)]
                                        : make_float2(0.0f, 0.0f);

        // Output is the state BEFORE the update. Lanes 0,1 write A,B:
        // adjacent float2 -> one coalesced 16B segment per group.
        if (writer) {
            op[glane] = isA ? make_float2(xaA, xbA) : make_float2(xaB, xbB);
        }
        op += QN;
        step2(u01.x, u01.y);

        if (writer) {
            op[glane] = isA ? make_float2(xaA, xbA) : make_float2(xaB, xbB);
        }
        op += QN;
        step2(u23.x, u23.y);

        u01 = un0;
        u23 = un1;
    }
}

extern "C" void kernel_launch(void* const* d_in, const int* in_sizes, int n_in,
                              void* d_out, int out_size, void* d_ws, size_t ws_size,
                              hipStream_t stream) {
    const float* x0 = (const float*)d_in[0];
    const float* u  = (const float*)d_in[1];
    const float* W1 = (const float*)d_in[2];
    const float* b1 = (const float*)d_in[3];
    const float* W2 = (const float*)d_in[4];
    const float* b2 = (const float*)d_in[5];
    float* out = (float*)d_out;

    // 4096 groups * 16 lanes = 65536 threads = 256 blocks of 256
    // = 1024 waves = 1 wave/SIMD, 2 trajectory chains per lane for ILP.
    const int threads = 256;
    const int blocks  = (QN / 2 * LPT) / threads;
    rk4_nss_kernel<<<blocks, threads, 0, stream>>>(x0, u, W1, b1, W2, b2, out);
}